// Round 4
// baseline (457.471 us; speedup 1.0000x reference)
//
#include <hip/hip_runtime.h>
#include <hip/hip_bf16.h>
#include <stdint.h>

typedef __attribute__((ext_vector_type(8))) short short8;   // 8 bf16 in 4 VGPRs
typedef __attribute__((ext_vector_type(4))) float floatx4;
typedef unsigned long long ull;

__device__ __forceinline__ floatx4 mfma_bf16(short8 a, short8 b, floatx4 c) {
  return __builtin_amdgcn_mfma_f32_16x16x32_bf16(a, b, c, 0, 0, 0);
}

// async global->LDS, 16B per lane; lds = wave-uniform base (lane lands at +lane*16)
__device__ __forceinline__ void async16(const void* g, void* lds) {
  __builtin_amdgcn_global_load_lds(
      (const __attribute__((address_space(1))) unsigned int*)g,
      (__attribute__((address_space(3))) unsigned int*)lds, 16, 0, 0);
}

// convert 8 contiguous fp32 -> 8 bf16 (one 16B store)
__device__ __forceinline__ void cvt8_store(const float* __restrict__ src,
                                           __hip_bfloat16* __restrict__ dst) {
  float4 a = *(const float4*)src;
  float4 b = *(const float4*)(src + 4);
  __hip_bfloat16 t[8];
  t[0] = __float2bfloat16(a.x); t[1] = __float2bfloat16(a.y);
  t[2] = __float2bfloat16(a.z); t[3] = __float2bfloat16(a.w);
  t[4] = __float2bfloat16(b.x); t[5] = __float2bfloat16(b.y);
  t[6] = __float2bfloat16(b.z); t[7] = __float2bfloat16(b.w);
  *(uint4*)dst = *(const uint4*)t;
}

// ---------------- prep: r<2048 Xs gather | <4096 WhhB | <6144 WihB | else fcWB
__global__ __launch_bounds__(256) void prep(
    const float* __restrict__ feat, const int* __restrict__ caps,
    const float* __restrict__ emb,  const float* __restrict__ Whh,
    const float* __restrict__ Wih,  const float* __restrict__ fcW,
    __hip_bfloat16* __restrict__ Xs,   __hip_bfloat16* __restrict__ WhhB,
    __hip_bfloat16* __restrict__ WihB, __hip_bfloat16* __restrict__ fcWB) {
  int tid = blockIdx.x * 256 + threadIdx.x;
  int r = tid >> 6;
  int ch = (tid & 63) * 8;
  const float* src;
  __hip_bfloat16* dst;
  if (r < 2048) {
    int t = r >> 6, b = r & 63;
    bool i64 = (caps[1] == 0) & (caps[3] == 0) & (caps[5] == 0) & (caps[7] == 0) &
               (caps[9] == 0) & (caps[11] == 0) & (caps[13] == 0);
    if (t == 0) {
      src = feat + (size_t)b * 512 + ch;
    } else {
      int idx = i64 ? caps[(size_t)(b * 32 + t) * 2] : caps[b * 32 + t];
      idx = idx < 0 ? 0 : (idx > 9999 ? 9999 : idx);
      src = emb + (size_t)idx * 512 + ch;
    }
    dst = Xs + (size_t)r * 512 + ch;
  } else if (r < 4096) {
    src = Whh + (size_t)(r - 2048) * 512 + ch;  dst = WhhB + (size_t)(r - 2048) * 512 + ch;
  } else if (r < 6144) {
    src = Wih + (size_t)(r - 4096) * 512 + ch;  dst = WihB + (size_t)(r - 4096) * 512 + ch;
  } else {
    src = fcW + (size_t)(r - 6144) * 512 + ch;  dst = fcWB + (size_t)(r - 6144) * 512 + ch;
  }
  cvt8_store(src, dst);
}

// ---------------- NT GEMM: C[M x N] = A[M x 512](bf16) * B[N x 512]^T + bias
// grid: x = jb (N tiles, fastest -> XCD spread over B tiles), y = ib (M tiles)
// mode 0: outF[row*ldc+col] = acc + b1[col] + b2[col]
// mode 1: outF[((row&63)*32+(row>>6))*ldc+col] = acc + b1[col]   (row = t*64+b -> [B,T,V])
__global__ __launch_bounds__(256) void gemm_nt(
    const __hip_bfloat16* __restrict__ A,
    const void* __restrict__ Bv,
    const float* __restrict__ b1,
    const float* __restrict__ b2,
    float* __restrict__ outF,
    int Nrows, int ldc, int mode, int bf16B) {
  const int K = 512;
  __shared__ __align__(16) __hip_bfloat16 As[128 * 32];
  __shared__ __align__(16) __hip_bfloat16 Bs[128 * 32];
  const int tid = threadIdx.x;
  const int jb = blockIdx.x, ib = blockIdx.y;
  const int w = tid >> 6, l = tid & 63, lr = l & 15, lq = l >> 4;
  const int wr = (w & 1) * 64, wc = (w >> 1) * 64;
  floatx4 acc[4][4] = {};
  for (int kt = 0; kt < 16; ++kt) {
    const int k0 = kt * 32;
#pragma unroll
    for (int it = 0; it < 2; ++it) {
      const int flat0 = it * 256 + w * 64;   // wave-uniform LDS base index
      const int flat = flat0 + l;
      const int row = flat >> 2, c8 = (flat & 3) * 8;
      async16(A + (size_t)(ib * 128 + row) * K + k0 + c8, As + flat0 * 8);
      int rb = jb * 128 + row;
      if (rb > Nrows - 1) rb = Nrows - 1;    // clamp tail (dup reads; cols guarded on store)
      if (bf16B) {
        async16((const __hip_bfloat16*)Bv + (size_t)rb * K + k0 + c8, Bs + flat0 * 8);
      } else {
        cvt8_store((const float*)Bv + (size_t)rb * K + k0 + c8, Bs + flat * 8);
      }
    }
    __syncthreads();
    short8 af[4], bfr[4];
#pragma unroll
    for (int mt = 0; mt < 4; ++mt)
      af[mt] = *(const short8*)(As + (wr + mt * 16 + lr) * 32 + lq * 8);
#pragma unroll
    for (int nt = 0; nt < 4; ++nt)
      bfr[nt] = *(const short8*)(Bs + (wc + nt * 16 + lr) * 32 + lq * 8);
#pragma unroll
    for (int mt = 0; mt < 4; ++mt)
#pragma unroll
      for (int nt = 0; nt < 4; ++nt)
        acc[mt][nt] = mfma_bf16(af[mt], bfr[nt], acc[mt][nt]);
    __syncthreads();
  }
#pragma unroll
  for (int mt = 0; mt < 4; ++mt) {
#pragma unroll
    for (int nt = 0; nt < 4; ++nt) {
      int col = jb * 128 + wc + nt * 16 + lr;
      if (col < Nrows) {
        float bias = b1[col] + (b2 ? b2[col] : 0.f);
#pragma unroll
        for (int r = 0; r < 4; ++r) {
          int row = ib * 128 + wr + mt * 16 + lq * 4 + r;
          size_t orow = mode ? (size_t)((row & 63) * 32 + (row >> 6)) : (size_t)row;
          outF[orow * ldc + col] = acc[mt][nt][r] + bias;
        }
      }
    }
  }
}

// ---------------- LSTM: 64 blocks (4 bg x 16 ug). h moves as self-flagging 8B packets
// {2 bf16 | tag32 = t+1} via relaxed agent-scope atomics (ws is re-poisoned 0xAA every
// launch, so tag != poison and each (t,chunk) slot is write-once). No flags, no acks:
// producer chain = issue stores; consumer poll = detect + data in one transaction.
// Consumers pipeline 16 k-chunks (depth 4) and MFMA chunks as they arrive.
__global__ __launch_bounds__(256, 1) void lstm_seq(
    const float* __restrict__ xp,            // [32][64][2048] fp32 (biases included)
    const __hip_bfloat16* __restrict__ Whh,  // [2048][512] bf16
    __hip_bfloat16* __restrict__ hseq,       // [32][64][512] bf16 (plain, for gemm2)
    ull* __restrict__ hpk) {                 // [32][4][16][16][16] 8B packets (4 MB)
  const int bg = blockIdx.x >> 4;   // 0..3  (16 batch rows)
  const int ug = blockIdx.x & 15;   // 0..15 (32 hidden units)
  const int tid = threadIdx.x;
  const int w = tid >> 6, l = tid & 63, lr = l & 15, lq = l >> 4;
  const int bl = tid >> 5, uu = tid & 31;
  const int pr = tid >> 4, pp = tid & 15;     // packer: row, packet
  __shared__ float gbuf[4][16][32];
  __shared__ __align__(16) __hip_bfloat16 hbuf[16][32];
  float c0 = 0.f, c1 = 0.f;

  // B fragments constant across t: preload all 32 (128 regs, unified VGPR/AGPR file)
  short8 B0[16], B1[16];
  {
    const __hip_bfloat16* w0 = Whh + (size_t)(w * 512 + ug * 32 + lr) * 512 + lq * 8;
    const __hip_bfloat16* w1 = w0 + (size_t)16 * 512;
#pragma unroll
    for (int kk = 0; kk < 16; ++kk) {
      B0[kk] = *(const short8*)(w0 + kk * 32);
      B1[kk] = *(const short8*)(w1 + kk * 32);
    }
  }

  for (int t = 0; t < 32; ++t) {
    // prefetch this step's xp (h-independent; in flight during the poll)
    const float* xr0 = xp + ((size_t)t * 64 + bg * 16 + bl) * 2048 + ug * 32 + uu;
    const float* xr1 = xr0 + (size_t)8 * 2048;
    float xi0 = xr0[0], xf0 = xr0[512], xg0 = xr0[1024], xo0 = xr0[1536];
    float xi1 = xr1[0], xf1 = xr1[512], xg1 = xr1[1024], xo1 = xr1[1536];

    floatx4 a0 = {}, a1 = {};
    if (t > 0) {
      const unsigned tagv = (unsigned)t;   // producer at t-1 wrote tag = (t-1)+1 = t
      // lane base: [t-1][bg][cg][lr][lq*4 + j], chunk stride = 256 packets
      const ull* pb = hpk + ((((size_t)(t - 1) * 4 + bg) * 16 * 16 + lr) * 16) + lq * 4;
      ull q[4][4];
#pragma unroll
      for (int g = 0; g < 4; ++g)
#pragma unroll
        for (int j = 0; j < 4; ++j)
          q[g][j] = __hip_atomic_load(pb + g * 256 + j,
                                      __ATOMIC_RELAXED, __HIP_MEMORY_SCOPE_AGENT);
      for (int cg = 0; cg < 16; ++cg) {
        const int g = cg & 3;
        for (;;) {
          bool ok = ((unsigned)(q[g][0] >> 32) == tagv) &
                    ((unsigned)(q[g][1] >> 32) == tagv) &
                    ((unsigned)(q[g][2] >> 32) == tagv) &
                    ((unsigned)(q[g][3] >> 32) == tagv);
          if (__all((int)ok)) break;
#pragma unroll
          for (int j = 0; j < 4; ++j)
            q[g][j] = __hip_atomic_load(pb + cg * 256 + j,
                                        __ATOMIC_RELAXED, __HIP_MEMORY_SCOPE_AGENT);
        }
        union { unsigned i[4]; short8 v; } av;
#pragma unroll
        for (int j = 0; j < 4; ++j) av.i[j] = (unsigned)q[g][j];
        a0 = mfma_bf16(av.v, B0[cg], a0);
        a1 = mfma_bf16(av.v, B1[cg], a1);
        if (cg + 4 < 16) {   // refill this slot with chunk cg+4
#pragma unroll
          for (int j = 0; j < 4; ++j)
            q[g][j] = __hip_atomic_load(pb + (cg + 4) * 256 + j,
                                        __ATOMIC_RELAXED, __HIP_MEMORY_SCOPE_AGENT);
        }
      }
    }
#pragma unroll
    for (int r = 0; r < 4; ++r) {
      gbuf[w][lq * 4 + r][lr] = a0[r];
      gbuf[w][lq * 4 + r][16 + lr] = a1[r];
    }
    __syncthreads();
    {
      float gi = gbuf[0][bl][uu] + xi0, gf = gbuf[1][bl][uu] + xf0;
      float gg = gbuf[2][bl][uu] + xg0, go = gbuf[3][bl][uu] + xo0;
      float c = 1.f / (1.f + __expf(-gf)) * c0 + 1.f / (1.f + __expf(-gi)) * tanhf(gg);
      c0 = c;
      hbuf[bl][uu] = __float2bfloat16(1.f / (1.f + __expf(-go)) * tanhf(c));
    }
    {
      float gi = gbuf[0][bl + 8][uu] + xi1, gf = gbuf[1][bl + 8][uu] + xf1;
      float gg = gbuf[2][bl + 8][uu] + xg1, go = gbuf[3][bl + 8][uu] + xo1;
      float c = 1.f / (1.f + __expf(-gf)) * c1 + 1.f / (1.f + __expf(-gi)) * tanhf(gg);
      c1 = c;
      hbuf[bl + 8][uu] = __float2bfloat16(1.f / (1.f + __expf(-go)) * tanhf(c));
    }
    __syncthreads();
    // publish packets: thread (pr,pp) -> cols 2pp,2pp+1 of row pr; tag = t+1
    {
      unsigned lo = *(const unsigned*)&hbuf[pr][pp * 2];
      ull pkt = (ull)lo | ((ull)(unsigned)(t + 1) << 32);
      ull* dst = hpk + ((((size_t)t * 4 + bg) * 16 + ug) * 16 + pr) * 16 + pp;
      __hip_atomic_store(dst, pkt, __ATOMIC_RELAXED, __HIP_MEMORY_SCOPE_AGENT);
    }
    // plain h store for gemm2 (kernel-end writeback makes it visible)
    if (tid < 64) {
      int r = tid >> 2, seg = tid & 3;
      *(uint4*)(hseq + (size_t)(t * 64 + bg * 16 + r) * 512 + ug * 32 + seg * 8) =
          *(const uint4*)&hbuf[r][seg * 8];
    }
    // no ack, no barrier: hbuf rewritten only after next step's __syncthreads,
    // and packet visibility is the consumers' poll's problem
  }
}

extern "C" void kernel_launch(void* const* d_in, const int* in_sizes, int n_in,
                              void* d_out, int out_size, void* d_ws, size_t ws_size,
                              hipStream_t stream) {
  const float* feat = (const float*)d_in[0];
  const int* caps   = (const int*)d_in[1];
  const float* emb  = (const float*)d_in[2];
  const float* Wih  = (const float*)d_in[3];
  const float* Whh  = (const float*)d_in[4];
  const float* bih  = (const float*)d_in[5];
  const float* bhh  = (const float*)d_in[6];
  const float* fcW  = (const float*)d_in[7];
  const float* fcb  = (const float*)d_in[8];
  float* out = (float*)d_out;                  // [64,32,10000] fp32

  const size_t MB = 1048576;
  char* ws = (char*)d_ws;
  // lifetime-overlapped layout:
  //  @0:  Xs (2MB, prep->gemm1) and WihB @2MB (prep->gemm1); both dead before lstm,
  //       region reused as hpk (4MB) by lstm->(consumed in lstm only)
  __hip_bfloat16* Xs   = (__hip_bfloat16*)(ws);             // 2 MB  [2048,512]
  __hip_bfloat16* WihB = (__hip_bfloat16*)(ws + 2 * MB);    // 2 MB
  ull*            hpk  = (ull*)(ws);                        // 4 MB (reuse, lstm only)
  __hip_bfloat16* WhhB = (__hip_bfloat16*)(ws + 4 * MB);    // 2 MB (prep->lstm)
  float*          xprj = (float*)(ws + 6 * MB);             // 16 MB [2048,2048]
  __hip_bfloat16* hseq = (__hip_bfloat16*)(ws + 22 * MB);   // 2 MB  [2048,512]
  __hip_bfloat16* fcWB = (__hip_bfloat16*)(ws + 24 * MB);   // 9.77 MB (prep->gemm2)
  const size_t need = 24 * MB + (size_t)10000 * 512 * 2;
  const int doFc = (ws_size >= need);

  int rows = doFc ? 16144 : 6144;   // Xs 2048 | WhhB 2048 | WihB 2048 | fcWB 10000
  prep<<<rows / 4, 256, 0, stream>>>(feat, caps, emb, Whh, Wih, fcW,
                                     Xs, WhhB, WihB, fcWB);

  gemm_nt<<<dim3(16, 16), 256, 0, stream>>>(Xs, WihB, bih, bhh, xprj,
                                            2048, 2048, 0, 1);

  lstm_seq<<<64, 256, 0, stream>>>(xprj, WhhB, hseq, hpk);

  if (doFc)
    gemm_nt<<<dim3(79, 16), 256, 0, stream>>>(hseq, fcWB, fcb, nullptr, out,
                                              10000, 10000, 1, 1);
  else
    gemm_nt<<<dim3(79, 16), 256, 0, stream>>>(hseq, fcW, fcb, nullptr, out,
                                              10000, 10000, 1, 0);
}

// Round 5
// 374.278 us; speedup vs baseline: 1.2223x; 1.2223x over previous
//
#include <hip/hip_runtime.h>
#include <hip/hip_bf16.h>
#include <stdint.h>

typedef __attribute__((ext_vector_type(8))) short short8;   // 8 bf16 in 4 VGPRs
typedef __attribute__((ext_vector_type(4))) float floatx4;
typedef unsigned long long ull;

__device__ __forceinline__ floatx4 mfma_bf16(short8 a, short8 b, floatx4 c) {
  return __builtin_amdgcn_mfma_f32_16x16x32_bf16(a, b, c, 0, 0, 0);
}

// async global->LDS, 16B per lane; lds = wave-uniform base (lane lands at +lane*16)
__device__ __forceinline__ void async16(const void* g, void* lds) {
  __builtin_amdgcn_global_load_lds(
      (const __attribute__((address_space(1))) unsigned int*)g,
      (__attribute__((address_space(3))) unsigned int*)lds, 16, 0, 0);
}

// convert 8 contiguous fp32 -> 8 bf16 (one 16B store)
__device__ __forceinline__ void cvt8_store(const float* __restrict__ src,
                                           __hip_bfloat16* __restrict__ dst) {
  float4 a = *(const float4*)src;
  float4 b = *(const float4*)(src + 4);
  __hip_bfloat16 t[8];
  t[0] = __float2bfloat16(a.x); t[1] = __float2bfloat16(a.y);
  t[2] = __float2bfloat16(a.z); t[3] = __float2bfloat16(a.w);
  t[4] = __float2bfloat16(b.x); t[5] = __float2bfloat16(b.y);
  t[6] = __float2bfloat16(b.z); t[7] = __float2bfloat16(b.w);
  *(uint4*)dst = *(const uint4*)t;
}

// ---------------- prep: r<2048 Xs gather | <4096 WhhB | <6144 WihB | else fcWB
__global__ __launch_bounds__(256) void prep(
    const float* __restrict__ feat, const int* __restrict__ caps,
    const float* __restrict__ emb,  const float* __restrict__ Whh,
    const float* __restrict__ Wih,  const float* __restrict__ fcW,
    __hip_bfloat16* __restrict__ Xs,   __hip_bfloat16* __restrict__ WhhB,
    __hip_bfloat16* __restrict__ WihB, __hip_bfloat16* __restrict__ fcWB) {
  int tid = blockIdx.x * 256 + threadIdx.x;
  int r = tid >> 6;
  int ch = (tid & 63) * 8;
  const float* src;
  __hip_bfloat16* dst;
  if (r < 2048) {
    int t = r >> 6, b = r & 63;
    bool i64 = (caps[1] == 0) & (caps[3] == 0) & (caps[5] == 0) & (caps[7] == 0) &
               (caps[9] == 0) & (caps[11] == 0) & (caps[13] == 0);
    if (t == 0) {
      src = feat + (size_t)b * 512 + ch;
    } else {
      int idx = i64 ? caps[(size_t)(b * 32 + t) * 2] : caps[b * 32 + t];
      idx = idx < 0 ? 0 : (idx > 9999 ? 9999 : idx);
      src = emb + (size_t)idx * 512 + ch;
    }
    dst = Xs + (size_t)r * 512 + ch;
  } else if (r < 4096) {
    src = Whh + (size_t)(r - 2048) * 512 + ch;  dst = WhhB + (size_t)(r - 2048) * 512 + ch;
  } else if (r < 6144) {
    src = Wih + (size_t)(r - 4096) * 512 + ch;  dst = WihB + (size_t)(r - 4096) * 512 + ch;
  } else {
    src = fcW + (size_t)(r - 6144) * 512 + ch;  dst = fcWB + (size_t)(r - 6144) * 512 + ch;
  }
  cvt8_store(src, dst);
}

// ---------------- NT GEMM: C[M x N] = A[M x 512](bf16) * B[N x 512]^T + bias
// grid: x = jb (N tiles, fastest -> XCD spread over B tiles), y = ib (M tiles)
// mode 0: outF[row*ldc+col] = acc + b1[col] + b2[col]
// mode 1: outF[((row&63)*32+(row>>6))*ldc+col] = acc + b1[col]   (row = t*64+b -> [B,T,V])
__global__ __launch_bounds__(256) void gemm_nt(
    const __hip_bfloat16* __restrict__ A,
    const void* __restrict__ Bv,
    const float* __restrict__ b1,
    const float* __restrict__ b2,
    float* __restrict__ outF,
    int Nrows, int ldc, int mode, int bf16B) {
  const int K = 512;
  __shared__ __align__(16) __hip_bfloat16 As[128 * 32];
  __shared__ __align__(16) __hip_bfloat16 Bs[128 * 32];
  const int tid = threadIdx.x;
  const int jb = blockIdx.x, ib = blockIdx.y;
  const int w = tid >> 6, l = tid & 63, lr = l & 15, lq = l >> 4;
  const int wr = (w & 1) * 64, wc = (w >> 1) * 64;
  floatx4 acc[4][4] = {};
  for (int kt = 0; kt < 16; ++kt) {
    const int k0 = kt * 32;
#pragma unroll
    for (int it = 0; it < 2; ++it) {
      const int flat0 = it * 256 + w * 64;   // wave-uniform LDS base index
      const int flat = flat0 + l;
      const int row = flat >> 2, c8 = (flat & 3) * 8;
      async16(A + (size_t)(ib * 128 + row) * K + k0 + c8, As + flat0 * 8);
      int rb = jb * 128 + row;
      if (rb > Nrows - 1) rb = Nrows - 1;    // clamp tail (dup reads; cols guarded on store)
      if (bf16B) {
        async16((const __hip_bfloat16*)Bv + (size_t)rb * K + k0 + c8, Bs + flat0 * 8);
      } else {
        cvt8_store((const float*)Bv + (size_t)rb * K + k0 + c8, Bs + flat * 8);
      }
    }
    __syncthreads();
    short8 af[4], bfr[4];
#pragma unroll
    for (int mt = 0; mt < 4; ++mt)
      af[mt] = *(const short8*)(As + (wr + mt * 16 + lr) * 32 + lq * 8);
#pragma unroll
    for (int nt = 0; nt < 4; ++nt)
      bfr[nt] = *(const short8*)(Bs + (wc + nt * 16 + lr) * 32 + lq * 8);
#pragma unroll
    for (int mt = 0; mt < 4; ++mt)
#pragma unroll
      for (int nt = 0; nt < 4; ++nt)
        acc[mt][nt] = mfma_bf16(af[mt], bfr[nt], acc[mt][nt]);
    __syncthreads();
  }
#pragma unroll
  for (int mt = 0; mt < 4; ++mt) {
#pragma unroll
    for (int nt = 0; nt < 4; ++nt) {
      int col = jb * 128 + wc + nt * 16 + lr;
      if (col < Nrows) {
        float bias = b1[col] + (b2 ? b2[col] : 0.f);
#pragma unroll
        for (int r = 0; r < 4; ++r) {
          int row = ib * 128 + wr + mt * 16 + lq * 4 + r;
          size_t orow = mode ? (size_t)((row & 63) * 32 + (row >> 6)) : (size_t)row;
          outF[orow * ldc + col] = acc[mt][nt][r] + bias;
        }
      }
    }
  }
}

// ---------------- LSTM: 64 blocks (4 bg x 16 ug). Round-3 structure (atomic h via
// LLC) but per-producer FLAG WORDS instead of a shared fetch_add counter:
// producer = h-stores -> s_waitcnt(0) -> one flag store (no RMW serialization);
// consumer = 16 lanes poll the 16 flags (one 64B line) in parallel, then bulk-load h.
__global__ __launch_bounds__(256, 1) void lstm_seq(
    const float* __restrict__ xp,            // [32][64][2048] fp32 (biases included)
    const __hip_bfloat16* __restrict__ Whh,  // [2048][512] bf16
    __hip_bfloat16* __restrict__ hseq,       // [32][64][512] bf16 (atomic, also gemm2 A)
    unsigned* __restrict__ flags) {          // [32][64] uints; (t,bg) -> one 64B line
  const int bg = blockIdx.x >> 4;   // 0..3  (16 batch rows)
  const int ug = blockIdx.x & 15;   // 0..15 (32 hidden units)
  const int tid = threadIdx.x;
  const int w = tid >> 6, l = tid & 63, lr = l & 15, lq = l >> 4;
  const int bl = tid >> 5, uu = tid & 31;
  __shared__ float gbuf[4][16][32];
  __shared__ __align__(8) __hip_bfloat16 hbuf[16][32];
  float c0 = 0.f, c1 = 0.f;

  // B fragments constant across t: preload all 32 (128 regs, unified VGPR/AGPR file)
  short8 B0[16], B1[16];
  {
    const __hip_bfloat16* w0 = Whh + (size_t)(w * 512 + ug * 32 + lr) * 512 + lq * 8;
    const __hip_bfloat16* w1 = w0 + (size_t)16 * 512;
#pragma unroll
    for (int kk = 0; kk < 16; ++kk) {
      B0[kk] = *(const short8*)(w0 + kk * 32);
      B1[kk] = *(const short8*)(w1 + kk * 32);
    }
  }

  for (int t = 0; t < 32; ++t) {
    // prefetch this step's xp (h-independent; in flight during the poll)
    const float* xr0 = xp + ((size_t)t * 64 + bg * 16 + bl) * 2048 + ug * 32 + uu;
    const float* xr1 = xr0 + (size_t)8 * 2048;
    float xi0 = xr0[0], xf0 = xr0[512], xg0 = xr0[1024], xo0 = xr0[1536];
    float xi1 = xr1[0], xf1 = xr1[512], xg1 = xr1[1024], xo1 = xr1[1536];

    floatx4 a0 = {}, a1 = {};
    if (t > 0) {
      const unsigned tagv = (unsigned)t;   // producer at step t-1 stored t
      const unsigned* f = flags + (size_t)(t - 1) * 64 + bg * 16;
      // every wave polls: lanes 0..15 each own one producer's flag (one LLC line)
      for (;;) {
        unsigned v = (l < 16)
            ? __hip_atomic_load(f + l, __ATOMIC_RELAXED, __HIP_MEMORY_SCOPE_AGENT)
            : tagv;
        if (__all((int)(v == tagv))) break;
        __builtin_amdgcn_s_sleep(1);
      }
      __builtin_amdgcn_sched_barrier(0);   // keep h loads after the poll exit
      const ull* hp = (const ull*)(hseq + (size_t)((t - 1) * 64 + bg * 16 + lr) * 512);
#pragma unroll
      for (int kk = 0; kk < 16; ++kk) {
        union { ull u[2]; short8 v; } hv;
        hv.u[0] = __hip_atomic_load(hp + kk * 8 + lq * 2,
                                    __ATOMIC_RELAXED, __HIP_MEMORY_SCOPE_AGENT);
        hv.u[1] = __hip_atomic_load(hp + kk * 8 + lq * 2 + 1,
                                    __ATOMIC_RELAXED, __HIP_MEMORY_SCOPE_AGENT);
        a0 = mfma_bf16(hv.v, B0[kk], a0);
        a1 = mfma_bf16(hv.v, B1[kk], a1);
      }
    }
#pragma unroll
    for (int r = 0; r < 4; ++r) {
      gbuf[w][lq * 4 + r][lr] = a0[r];
      gbuf[w][lq * 4 + r][16 + lr] = a1[r];
    }
    __syncthreads();
    {
      float gi = gbuf[0][bl][uu] + xi0, gf = gbuf[1][bl][uu] + xf0;
      float gg = gbuf[2][bl][uu] + xg0, go = gbuf[3][bl][uu] + xo0;
      float c = 1.f / (1.f + __expf(-gf)) * c0 + 1.f / (1.f + __expf(-gi)) * tanhf(gg);
      c0 = c;
      hbuf[bl][uu] = __float2bfloat16(1.f / (1.f + __expf(-go)) * tanhf(c));
    }
    {
      float gi = gbuf[0][bl + 8][uu] + xi1, gf = gbuf[1][bl + 8][uu] + xf1;
      float gg = gbuf[2][bl + 8][uu] + xg1, go = gbuf[3][bl + 8][uu] + xo1;
      float c = 1.f / (1.f + __expf(-gf)) * c1 + 1.f / (1.f + __expf(-gi)) * tanhf(gg);
      c1 = c;
      hbuf[bl + 8][uu] = __float2bfloat16(1.f / (1.f + __expf(-go)) * tanhf(c));
    }
    __syncthreads();
    if (tid < 128) {   // 16 rows x 8 ull = our 16x32 h slice -> LLC
      int r = tid >> 3, g = tid & 7;
      ull val = *(const ull*)(&hbuf[r][g * 4]);
      ull* dst = (ull*)(hseq + (size_t)(t * 64 + bg * 16 + r) * 512 + ug * 32) + g;
      __hip_atomic_store(dst, val, __ATOMIC_RELAXED, __HIP_MEMORY_SCOPE_AGENT);
    }
    __builtin_amdgcn_s_waitcnt(0);   // h stores acked at LLC (per wave)
    __syncthreads();                 // all waves done
    if (tid == 0)                    // fire-and-forget: one plain flag store, no RMW
      __hip_atomic_store(flags + (size_t)t * 64 + bg * 16 + ug, (unsigned)(t + 1),
                         __ATOMIC_RELAXED, __HIP_MEMORY_SCOPE_AGENT);
  }
}

extern "C" void kernel_launch(void* const* d_in, const int* in_sizes, int n_in,
                              void* d_out, int out_size, void* d_ws, size_t ws_size,
                              hipStream_t stream) {
  const float* feat = (const float*)d_in[0];
  const int* caps   = (const int*)d_in[1];
  const float* emb  = (const float*)d_in[2];
  const float* Wih  = (const float*)d_in[3];
  const float* Whh  = (const float*)d_in[4];
  const float* bih  = (const float*)d_in[5];
  const float* bhh  = (const float*)d_in[6];
  const float* fcW  = (const float*)d_in[7];
  const float* fcb  = (const float*)d_in[8];
  float* out = (float*)d_out;                  // [64,32,10000] fp32

  const size_t MB = 1048576;
  char* ws = (char*)d_ws;
  __hip_bfloat16* Xs   = (__hip_bfloat16*)(ws);             // 2 MB  [2048,512]
  __hip_bfloat16* WihB = (__hip_bfloat16*)(ws + 2 * MB);    // 2 MB
  __hip_bfloat16* WhhB = (__hip_bfloat16*)(ws + 4 * MB);    // 2 MB
  float*          xprj = (float*)(ws + 6 * MB);             // 16 MB [2048,2048]
  __hip_bfloat16* hseq = (__hip_bfloat16*)(ws + 22 * MB);   // 2 MB  [2048,512]
  unsigned*       flags= (unsigned*)(ws + 24 * MB);         // 8 KB [32][64]
  __hip_bfloat16* fcWB = (__hip_bfloat16*)(ws + 24 * MB + 65536);  // 9.77 MB
  const size_t need = 24 * MB + 65536 + (size_t)10000 * 512 * 2;
  const int doFc = (ws_size >= need);

  hipMemsetAsync(flags, 0, 8192, stream);   // pre-warm + zero (tags are 1..32)

  int rows = doFc ? 16144 : 6144;   // Xs 2048 | WhhB 2048 | WihB 2048 | fcWB 10000
  prep<<<rows / 4, 256, 0, stream>>>(feat, caps, emb, Whh, Wih, fcW,
                                     Xs, WhhB, WihB, fcWB);

  gemm_nt<<<dim3(16, 16), 256, 0, stream>>>(Xs, WihB, bih, bhh, xprj,
                                            2048, 2048, 0, 1);

  lstm_seq<<<64, 256, 0, stream>>>(xprj, WhhB, hseq, flags);

  if (doFc)
    gemm_nt<<<dim3(79, 16), 256, 0, stream>>>(hseq, fcWB, fcb, nullptr, out,
                                              10000, 10000, 1, 1);
  else
    gemm_nt<<<dim3(79, 16), 256, 0, stream>>>(hseq, fcW, fcb, nullptr, out,
                                              10000, 10000, 1, 0);
}